// Round 2
// baseline (805.231 us; speedup 1.0000x reference)
//
#include <hip/hip_runtime.h>

typedef _Float16 f16;
typedef _Float16 f16x2 __attribute__((ext_vector_type(2)));
typedef _Float16 f16x4 __attribute__((ext_vector_type(4)));
typedef _Float16 f16x8 __attribute__((ext_vector_type(8)));
typedef float f32x4 __attribute__((ext_vector_type(4)));

static __device__ __forceinline__ f32x4 mfma16(f16x8 a, f16x8 b, f32x4 c) {
  return __builtin_amdgcn_mfma_f32_16x16x32_f16(a, b, c, 0, 0, 0);
}

#if __has_builtin(__builtin_amdgcn_fdot2)
static __device__ __forceinline__ float fdot2(f16x2 a, f16x2 b, float c) {
  return __builtin_amdgcn_fdot2(a, b, c, false);
}
#else
static __device__ __forceinline__ float fdot2(f16x2 a, f16x2 b, float c) {
  return c + (float)a[0] * (float)b[0] + (float)a[1] * (float)b[1];
}
#endif

static __device__ __forceinline__ f16x2 pick2(f16x8 v, int p) {
  f16x2 r; r[0] = v[2 * p]; r[1] = v[2 * p + 1]; return r;
}
static __device__ __forceinline__ f16x8 bcast8(float x) {
  f16 h = (f16)x; f16x8 r;
  #pragma unroll
  for (int e = 0; e < 8; e++) r[e] = h;
  return r;
}

#define GLD16(gp, lp) __builtin_amdgcn_global_load_lds( \
    (const __attribute__((address_space(1))) unsigned int*)(gp), \
    (__attribute__((address_space(3))) unsigned int*)(lp), 16, 0, 0)

// ---------------- K0: weight prep (fp32 -> f16, transposed to [n][k]) + f16 LN consts ----------------
__global__ __launch_bounds__(256) void k0_prep(
    const float* __restrict__ W0, const float* __restrict__ b0,
    const float* __restrict__ W1, const float* __restrict__ b1,
    const float* __restrict__ W2, const float* __restrict__ b2,
    const float* __restrict__ W3, const float* __restrict__ b3,
    const float* __restrict__ Wf, const float* __restrict__ Ws,
    const float* __restrict__ g1, const float* __restrict__ be1,
    const float* __restrict__ g2, const float* __restrict__ be2,
    f16* __restrict__ wqkvT, f16* __restrict__ wfT, f16* __restrict__ wsT,
    float* __restrict__ bqkv,
    f16* __restrict__ g1f, f16* __restrict__ b1f,
    f16* __restrict__ g2f, f16* __restrict__ b2f)
{
  int t = blockIdx.x * 256 + threadIdx.x;
  if (t < 49152) {                       // wqkvT [384][128], n = h*96 + j
    int n = t >> 7, k = t & 127;
    int h = n / 96, nn = n - h * 96;
    const float* W = (h == 0) ? W0 : (h == 1) ? W1 : (h == 2) ? W2 : W3;
    wqkvT[t] = (f16)W[k * 96 + nn];
  } else if (t < 114688) {               // wfT [256][256]
    int i = t - 49152;
    int n = i >> 8, k = i & 255;
    wfT[i] = (f16)Wf[k * 256 + n];
  } else if (t < 901120) {               // wsT [256][3072]
    int i = t - 114688;
    int n = i / 3072, k = i - n * 3072;
    wsT[i] = (f16)Ws[k * 256 + n];
  } else if (t < 901504) {               // bqkv [384] fp32
    int i = t - 901120;
    int h = i / 96, j = i - h * 96;
    const float* bp = (h == 0) ? b0 : (h == 1) ? b1 : (h == 2) ? b2 : b3;
    bqkv[i] = bp[j];
  } else if (t < 901760) { g1f[t - 901504] = (f16)g1[t - 901504]; }
  else if (t < 902016)   { b1f[t - 901760] = (f16)be1[t - 901760]; }
  else if (t < 902528)   { g2f[t - 902016] = (f16)g2[t - 902016]; }
  else if (t < 903040)   { b2f[t - 902528] = (f16)be2[t - 902528]; }
}

// ---------------- K1: fused qkv + attention + LN1 + Wf + LN2 -> f_norm (f16) ----------------
// LDS aliasing map (qkv buffer, per row, 384 natural cols, pitch QP):
//   cols h*96+ 0..31 : Q[h]   -> overwritten by attn head h after P3 (live to P8)
//   cols h*96+32..95 : K,V[h] -> dead after P3; reused as n/nWf segment h (64 cols each)
#define RB 8
#define SR 48
#define XP 136
#define QP 392

// n/nWf logical col c (0..255) -> physical col in qkv buffer
#define NPHYS(c) ((((c) >> 6) * 96) + 32 + ((c) & 63))
// attn logical col a (0..127) -> physical col (Q-slot)
#define APHYS(a) ((((a) >> 5) * 96) + ((a) & 31))

__global__ __launch_bounds__(256, 3) void k1_fused(
    const float* __restrict__ x,
    const f16* __restrict__ wqkvT, const f16* __restrict__ wfT,
    const float* __restrict__ bqkv,
    const f16* __restrict__ g1f, const f16* __restrict__ b1f,
    const float* __restrict__ bfv,
    const f16* __restrict__ g2f, const f16* __restrict__ b2f,
    f16* __restrict__ fbuf)
{
  __shared__ f16 xs[SR * XP];
  __shared__ f16 qkv[SR * QP];
  __shared__ float sum1[SR], sq1[SR], mu1[SR], rs1[SR];
  __shared__ float sum2[SR], sq2[SR], mu2[SR], rs2[SR];

  const int t = threadIdx.x;
  const int lane = t & 63, wave = t >> 6;
  const int lr = lane & 15, lq = lane >> 4;
  const int b0r = blockIdx.x * RB;

  if (t < SR) { sum1[t] = 0.f; sq1[t] = 0.f; sum2[t] = 0.f; sq2[t] = 0.f; }

  // ---- P1: load x -> xs (f16) ----
  {
    const float4* xg = (const float4*)(x + (size_t)b0r * 768);
    #pragma unroll
    for (int it = 0; it < 6; it++) {
      int i = t + it * 256;               // 1536 float4 = 48 rows x 32
      float4 v = xg[i];
      int r = i >> 5, c4 = i & 31;
      f16x4 o; o[0] = (f16)v.x; o[1] = (f16)v.y; o[2] = (f16)v.z; o[3] = (f16)v.w;
      *(f16x4*)&xs[r * XP + c4 * 4] = o;
    }
  }
  __syncthreads();

  // ---- P2: qkv = x @ Wqkv + b  (MFMA, M=48 N=384 K=128) ----
  {
    f32x4 acc[3][6];
    #pragma unroll
    for (int mt = 0; mt < 3; mt++)
      #pragma unroll
      for (int nt = 0; nt < 6; nt++) acc[mt][nt] = (f32x4){0.f, 0.f, 0.f, 0.f};
    #pragma unroll
    for (int k0 = 0; k0 < 128; k0 += 32) {
      f16x8 av[3];
      #pragma unroll
      for (int mt = 0; mt < 3; mt++)
        av[mt] = *(const f16x8*)&xs[(mt * 16 + lr) * XP + k0 + lq * 8];
      #pragma unroll
      for (int nt = 0; nt < 6; nt++) {
        int n = (wave * 6 + nt) * 16 + lr;
        f16x8 bv = *(const f16x8*)&wqkvT[n * 128 + k0 + lq * 8];
        #pragma unroll
        for (int mt = 0; mt < 3; mt++) acc[mt][nt] = mfma16(av[mt], bv, acc[mt][nt]);
      }
    }
    // epilogue: pair-pack via shfl (even lr lane stores cols c,c+1 as b32)
    #pragma unroll
    for (int nt = 0; nt < 6; nt++) {
      int c = (wave * 6 + nt) * 16 + lr;
      float bb = bqkv[c];
      #pragma unroll
      for (int mt = 0; mt < 3; mt++)
        #pragma unroll
        for (int rg = 0; rg < 4; rg++) {
          float v = acc[mt][nt][rg] + bb;
          float vp = __shfl_xor(v, 1);
          if (!(lr & 1)) {
            f16x2 pk; pk[0] = (f16)v; pk[1] = (f16)vp;
            int r = mt * 16 + lq * 4 + rg;
            *(f16x2*)&qkv[r * QP + c] = pk;
          }
        }
    }
  }
  __syncthreads();

  // ---- P3: attention (packed f16) + attn-part LN1 stats. threads 0..191 ----
  if (t < 192) {
    int b = t / 24;
    int rem = t - b * 24;
    int h = rem / 6, i = rem - (rem / 6) * 6;
    const f16* base = &qkv[(b * 6) * QP + h * 96];
    f16x8 q8[4];
    {
      const f16x8* Qr = (const f16x8*)(base + i * QP);
      #pragma unroll
      for (int u = 0; u < 4; u++) q8[u] = Qr[u];
    }
    float s[6];
    #pragma unroll
    for (int j = 0; j < 6; j++) {
      const f16x8* Kr = (const f16x8*)(base + j * QP + 32);
      float a = 0.f;
      #pragma unroll
      for (int u = 0; u < 4; u++) {
        f16x8 k8 = Kr[u];
        #pragma unroll
        for (int p = 0; p < 4; p++) a = fdot2(pick2(q8[u], p), pick2(k8, p), a);
      }
      s[j] = a;
    }
    f16x8 o8[4];
    #pragma unroll
    for (int u = 0; u < 4; u++)
      #pragma unroll
      for (int e = 0; e < 8; e++) o8[u][e] = (f16)0.f;
    #pragma unroll
    for (int j = 0; j < 6; j++) {
      const f16x8* Vr = (const f16x8*)(base + j * QP + 64);
      f16x8 s8 = bcast8(s[j]);
      #pragma unroll
      for (int u = 0; u < 4; u++) o8[u] += s8 * Vr[u];
    }
    // stats of this 32-col attn slice (row b*6+i)
    float so = 0.f, sso = 0.f;
    f16x2 one2; one2[0] = (f16)1.f; one2[1] = (f16)1.f;
    #pragma unroll
    for (int u = 0; u < 4; u++)
      #pragma unroll
      for (int p = 0; p < 4; p++) {
        f16x2 v2 = pick2(o8[u], p);
        so = fdot2(v2, one2, so);
        sso = fdot2(v2, v2, sso);
      }
    int r = b * 6 + i;
    atomicAdd(&sum1[r], so);
    atomicAdd(&sq1[r], sso);
    // write attn into this (row, head)'s Q-slot (only this thread ever reads it)
    f16x8* Ar = (f16x8*)&qkv[r * QP + h * 96];
    #pragma unroll
    for (int u = 0; u < 4; u++) Ar[u] = o8[u];
  } else if (t < 240) {
    // ---- P3b: x-part LN1 stats, one row per thread ----
    int r = t - 192;
    const f16x8* Xr = (const f16x8*)&xs[r * XP];
    float s = 0.f, ss = 0.f;
    f16x2 one2; one2[0] = (f16)1.f; one2[1] = (f16)1.f;
    #pragma unroll
    for (int u = 0; u < 16; u++) {
      f16x8 v8 = Xr[u];
      #pragma unroll
      for (int p = 0; p < 4; p++) {
        f16x2 v2 = pick2(v8, p);
        s = fdot2(v2, one2, s);
        ss = fdot2(v2, v2, ss);
      }
    }
    atomicAdd(&sum1[r], s);
    atomicAdd(&sq1[r], ss);
  }
  __syncthreads();

  if (t < SR) {
    float mu = sum1[t] * (1.f / 256.f);
    float var = sq1[t] * (1.f / 256.f) - mu * mu;
    mu1[t] = mu; rs1[t] = rsqrtf(var + 1e-5f);
  }
  __syncthreads();

  // ---- P5: n = LN1(m)*g1+b1 -> KV-slots ----
  #pragma unroll
  for (int it = 0; it < 3; it++) {
    int i = t + it * 256;                 // 768 tasks: 48 rows x 16 chunks(16 cols)
    int r = i >> 4, c0 = (i & 15) * 16;
    f16x8 mu8 = bcast8(mu1[r]), rs8 = bcast8(rs1[r]);
    #pragma unroll
    for (int u = 0; u < 2; u++) {
      int c = c0 + u * 8;
      f16x8 v8 = (c < 128) ? *(const f16x8*)&xs[r * XP + c]
                           : *(const f16x8*)&qkv[r * QP + APHYS(c - 128)];
      f16x8 g8 = *(const f16x8*)&g1f[c];
      f16x8 b8 = *(const f16x8*)&b1f[c];
      f16x8 o8 = ((v8 - mu8) * rs8) * g8 + b8;
      *(f16x8*)&qkv[r * QP + NPHYS(c)] = o8;
    }
  }
  __syncthreads();

  // ---- P6: nWf = n @ Wf (MFMA, M=48 N=256 K=256) ----
  f32x4 facc[3][4];
  #pragma unroll
  for (int mt = 0; mt < 3; mt++)
    #pragma unroll
    for (int nt = 0; nt < 4; nt++) facc[mt][nt] = (f32x4){0.f, 0.f, 0.f, 0.f};
  #pragma unroll
  for (int k0 = 0; k0 < 256; k0 += 32) {
    int cc = k0 + lq * 8;
    f16x8 av[3];
    #pragma unroll
    for (int mt = 0; mt < 3; mt++)
      av[mt] = *(const f16x8*)&qkv[(mt * 16 + lr) * QP + NPHYS(cc)];
    #pragma unroll
    for (int nt = 0; nt < 4; nt++) {
      int n = (wave * 4 + nt) * 16 + lr;
      f16x8 bv = *(const f16x8*)&wfT[n * 256 + k0 + lq * 8];
      #pragma unroll
      for (int mt = 0; mt < 3; mt++) facc[mt][nt] = mfma16(av[mt], bv, facc[mt][nt]);
    }
  }
  __syncthreads();   // all reads of n done

  // ---- P7: +bf, LN2 partial stats, pack-write nWf over KV-slots ----
  {
    #pragma unroll
    for (int nt = 0; nt < 4; nt++) {
      int c = (wave * 4 + nt) * 16 + lr;
      float bb = bfv[c];
      #pragma unroll
      for (int mt = 0; mt < 3; mt++)
        #pragma unroll
        for (int rg = 0; rg < 4; rg++) facc[mt][nt][rg] += bb;
    }
    #pragma unroll
    for (int mt = 0; mt < 3; mt++)
      #pragma unroll
      for (int rg = 0; rg < 4; rg++) {
        float s = 0.f, ss = 0.f;
        #pragma unroll
        for (int nt = 0; nt < 4; nt++) { float v = facc[mt][nt][rg]; s += v; ss += v * v; }
        #pragma unroll
        for (int off = 1; off < 16; off <<= 1) {
          s += __shfl_xor(s, off);
          ss += __shfl_xor(ss, off);
        }
        if (lr == 0) {
          int r = mt * 16 + lq * 4 + rg;
          atomicAdd(&sum2[r], s);
          atomicAdd(&sq2[r], ss);
        }
      }
    #pragma unroll
    for (int nt = 0; nt < 4; nt++) {
      int c = (wave * 4 + nt) * 16 + lr;
      int pc = NPHYS(c);
      #pragma unroll
      for (int mt = 0; mt < 3; mt++)
        #pragma unroll
        for (int rg = 0; rg < 4; rg++) {
          float v = facc[mt][nt][rg];
          float vp = __shfl_xor(v, 1);
          if (!(lr & 1)) {
            f16x2 pk; pk[0] = (f16)v; pk[1] = (f16)vp;
            int r = mt * 16 + lq * 4 + rg;
            *(f16x2*)&qkv[r * QP + pc] = pk;
          }
        }
    }
  }
  __syncthreads();
  if (t < SR) {
    float s = sum2[t] + sum1[t];          // m-part raw sums reused
    float ss = sq2[t] + sq1[t];
    float mu = s * (1.f / 512.f);
    float var = ss * (1.f / 512.f) - mu * mu;
    mu2[t] = mu; rs2[t] = rsqrtf(var + 1e-5f);
  }
  __syncthreads();

  // ---- P8: f_norm = LN2([nWf | x | attn])*g2+b2 -> fbuf (f16) ----
  {
    f16* fout = fbuf + (size_t)b0r * 3072;
    #pragma unroll
    for (int it = 0; it < 6; it++) {
      int i = t + it * 256;               // 1536 tasks: 48 rows x 32 chunks(16)
      int r = i >> 5, c0 = (i & 31) * 16;
      f16x8 mu8 = bcast8(mu2[r]), rs8 = bcast8(rs2[r]);
      #pragma unroll
      for (int u = 0; u < 2; u++) {
        int c = c0 + u * 8;
        f16x8 v8 = (c < 256) ? *(const f16x8*)&qkv[r * QP + NPHYS(c)]
                 : (c < 384) ? *(const f16x8*)&xs[r * XP + (c - 256)]
                             : *(const f16x8*)&qkv[r * QP + APHYS(c - 384)];
        f16x8 g8 = *(const f16x8*)&g2f[c];
        f16x8 b8 = *(const f16x8*)&b2f[c];
        f16x8 o8 = ((v8 - mu8) * rs8) * g8 + b8;
        *(f16x8*)(fout + (size_t)r * 512 + c) = o8;
      }
    }
  }
}

// ---------------- K2: out = relu(f @ Ws + bs)  (M=65536 K=3072 N=256) ----------------
// 128x128 tile, BK=32, full LDS double-buffer, single barrier per K-iter.
__global__ __launch_bounds__(256, 4) void k2_gemm(
    const f16* __restrict__ A, const f16* __restrict__ Bt,
    const float* __restrict__ bs, float* __restrict__ out)
{
  __shared__ f16 As[8192];    // 2 bufs x 128 rows x 32 cols
  __shared__ f16 Bs[8192];
  const int t = threadIdx.x;
  const int lane = t & 63, wave = t >> 6;
  const int lr = lane & 15, lq = lane >> 4;
  const int wm = wave & 1, wn = wave >> 1;
  const int m0 = blockIdx.y * 128, n0 = blockIdx.x * 128;

  // staging: thread covers 16B chunk t (rows 0..63) and t+256 (rows 64..127)
  const int r0 = t >> 2, kc = t & 3;
  const int r1 = r0 + 64;
  const int kg0 = kc ^ ((r0 >> 1) & 3);
  const int kg1 = kc ^ ((r1 >> 1) & 3);
  const f16* Ab = A + (size_t)m0 * 3072;
  const f16* Bb = Bt + (size_t)n0 * 3072;
  const int aofs0 = r0 * 3072 + kg0 * 8;
  const int aofs1 = r1 * 3072 + kg1 * 8;
  f16* lA0 = As + wave * 512;           // wave-uniform LDS bases (+lane*16B implicit)
  f16* lA1 = As + 2048 + wave * 512;
  f16* lB0 = Bs + wave * 512;
  f16* lB1 = Bs + 2048 + wave * 512;

  int aoff[4], boff[4];
  #pragma unroll
  for (int mt = 0; mt < 4; mt++) {
    int row = wm * 64 + mt * 16 + lr;
    aoff[mt] = (row * 4 + (lq ^ ((row >> 1) & 3))) * 8;
  }
  #pragma unroll
  for (int nt = 0; nt < 4; nt++) {
    int row = wn * 64 + nt * 16 + lr;
    boff[nt] = (row * 4 + (lq ^ ((row >> 1) & 3))) * 8;
  }

  f32x4 acc[4][4];
  #pragma unroll
  for (int mt = 0; mt < 4; mt++)
    #pragma unroll
    for (int nt = 0; nt < 4; nt++) acc[mt][nt] = (f32x4){0.f, 0.f, 0.f, 0.f};

#define STAGE(K0, BO) do { \
    GLD16(Ab + aofs0 + (K0), lA0 + (BO)); \
    GLD16(Ab + aofs1 + (K0), lA1 + (BO)); \
    GLD16(Bb + aofs0 + (K0) - r0 * 3072 + r0 * 3072, lB0 + (BO)); \
    GLD16(Bb + aofs1 + (K0), lB1 + (BO)); \
  } while (0)

  // prologue
  GLD16(Ab + aofs0, lA0); GLD16(Ab + aofs1, lA1);
  GLD16(Bb + aofs0, lB0); GLD16(Bb + aofs1, lB1);

  for (int ki = 0; ki < 96; ki++) {
    __syncthreads();                       // loads(ki) resident; prev compute done
    if (ki + 1 < 96) {
      const int k0 = (ki + 1) * 32;
      const int bo = ((ki + 1) & 1) * 4096;
      GLD16(Ab + aofs0 + k0, lA0 + bo);
      GLD16(Ab + aofs1 + k0, lA1 + bo);
      GLD16(Bb + aofs0 + k0, lB0 + bo);
      GLD16(Bb + aofs1 + k0, lB1 + bo);
    }
    const int bo = (ki & 1) * 4096;
    f16x8 av[4], bv[4];
    #pragma unroll
    for (int mt = 0; mt < 4; mt++) av[mt] = *(const f16x8*)&As[bo + aoff[mt]];
    #pragma unroll
    for (int nt = 0; nt < 4; nt++) bv[nt] = *(const f16x8*)&Bs[bo + boff[nt]];
    #pragma unroll
    for (int mt = 0; mt < 4; mt++)
      #pragma unroll
      for (int nt = 0; nt < 4; nt++)
        acc[mt][nt] = mfma16(av[mt], bv[nt], acc[mt][nt]);
  }
#undef STAGE

  #pragma unroll
  for (int nt = 0; nt < 4; nt++) {
    int col = n0 + wn * 64 + nt * 16 + lr;
    float bb = bs[col];
    #pragma unroll
    for (int mt = 0; mt < 4; mt++) {
      int rowb = m0 + wm * 64 + mt * 16 + lq * 4;
      #pragma unroll
      for (int rg = 0; rg < 4; rg++) {
        float v = acc[mt][nt][rg] + bb;
        out[(size_t)(rowb + rg) * 256 + col] = v > 0.f ? v : 0.f;
      }
    }
  }
}

// ---------------- launch ----------------
extern "C" void kernel_launch(void* const* d_in, const int* in_sizes, int n_in,
                              void* d_out, int out_size, void* d_ws, size_t ws_size,
                              hipStream_t stream) {
  (void)in_sizes; (void)n_in; (void)out_size; (void)ws_size;
  const float* x   = (const float*)d_in[0];
  const float* W0  = (const float*)d_in[1];  const float* b0  = (const float*)d_in[2];
  const float* W1  = (const float*)d_in[3];  const float* b1  = (const float*)d_in[4];
  const float* W2  = (const float*)d_in[5];  const float* b2  = (const float*)d_in[6];
  const float* W3  = (const float*)d_in[7];  const float* b3  = (const float*)d_in[8];
  const float* g1  = (const float*)d_in[9];  const float* be1 = (const float*)d_in[10];
  const float* Wf  = (const float*)d_in[11]; const float* bf  = (const float*)d_in[12];
  const float* g2  = (const float*)d_in[13]; const float* be2 = (const float*)d_in[14];
  const float* Ws  = (const float*)d_in[15]; const float* bs  = (const float*)d_in[16];
  float* out = (float*)d_out;

  char* ws = (char*)d_ws;
  f16*   wqkvT = (f16*)(ws);                 //   98304 B  [384][128]
  f16*   wfT   = (f16*)(ws + 98304);         //  131072 B  [256][256]
  f16*   wsT   = (f16*)(ws + 229376);        // 1572864 B  [256][3072]
  float* bqkv  = (float*)(ws + 1802240);     //    1536 B
  f16*   g1f   = (f16*)(ws + 1803776);       //     512 B
  f16*   b1f   = (f16*)(ws + 1804288);       //     512 B
  f16*   g2f   = (f16*)(ws + 1804800);       //    1024 B
  f16*   b2f   = (f16*)(ws + 1805824);       //    1024 B
  f16*   fbuf  = (f16*)(ws + 1806848);       // 402653184 B [65536*6][512]

  k0_prep<<<3528, 256, 0, stream>>>(W0, b0, W1, b1, W2, b2, W3, b3, Wf, Ws,
                                    g1, be1, g2, be2,
                                    wqkvT, wfT, wsT, bqkv, g1f, b1f, g2f, b2f);
  k1_fused<<<8192, 256, 0, stream>>>(x, wqkvT, wfT, bqkv, g1f, b1f, bf, g2f, b2f, fbuf);
  k2_gemm<<<dim3(2, 512), 256, 0, stream>>>(fbuf, wsT, bs, out);
}